// Round 8
// baseline (694.367 us; speedup 1.0000x reference)
//
#include <hip/hip_runtime.h>
#include <cstddef>
#include <cstdint>

#define DEVI __device__ __forceinline__

namespace {

typedef _Float16 f16;
typedef _Float16 half4 __attribute__((ext_vector_type(4)));
typedef _Float16 half8 __attribute__((ext_vector_type(8)));
typedef _Float16 f16x2 __attribute__((ext_vector_type(2)));
typedef float floatx4 __attribute__((ext_vector_type(4)));

typedef const __attribute__((address_space(1))) void gvoid;
typedef __attribute__((address_space(3))) void lvoid;
#define GLL(gp, lp) __builtin_amdgcn_global_load_lds((gvoid*)(gp), (lvoid*)(lp), 16, 0, 0)

constexpr float kLog2e = 1.4426950408889634f;
constexpr float kLn2   = 0.6931471805599453f;
DEVI float fexp2_(float x) { return __builtin_amdgcn_exp2f(x); }
DEVI float frcp_(float x)  { return __builtin_amdgcn_rcpf(x); }
DEVI float flog2_(float x) { return __builtin_amdgcn_logf(x); }
DEVI float fsig_(float v)  { return frcp_(1.f + fexp2_(-kLog2e * v)); }
DEVI float ftanh_(float v) { return 1.f - 2.f * frcp_(1.f + fexp2_(2.f * kLog2e * v)); }
DEVI float fsoftplus_(float v) {
  return fmaxf(v, 0.f) + kLn2 * flog2_(1.f + fexp2_(-kLog2e * fabsf(v)));
}

// ---------------------------------------------------------------------------
struct CvtTab { const float* s[14]; f16* d[14]; int n4[14]; };

__global__ __launch_bounds__(256)
void cvt_k(CvtTab tab) {
  const int e = blockIdx.y;
  const int n4 = tab.n4[e];
  const float4* s = (const float4*)tab.s[e];
  f16* d = tab.d[e];
  for (int i = blockIdx.x * 256 + threadIdx.x; i < n4; i += gridDim.x * 256) {
    const float4 v = s[i];
    half4 o = {(f16)v.x, (f16)v.y, (f16)v.z, (f16)v.w};
    *(half4*)(d + (size_t)i * 4) = o;
  }
}

// ---------------------------------------------------------------------------
// fp16 MFMA GEMM, 8-phase-style schedule (T3/T5 port):
// BM=BN=256, BK=64; 512 thr = 8 waves (2Mx4N); wave tile 128x64;
// MFMA 16x16x32 f16, acc floatx4 acc[8][4] (128 VGPR).
// LDS: 2 slots x (A 32K + B 32K) = 128 KB, chunk-XOR swizzle (c ^= row&7).
// Per K-tile t (slot s=t&1), 4 phases p:
//   {2xGLL stage chunk p of tile t+1 -> slot s^1;  ds_read frags (8 or 4);
//    s_barrier; setprio(1); 16 MFMA; setprio(0); s_barrier}
// boundary: lgkmcnt(0) vmcnt(0) + barrier (drain issued >=1 phase earlier).
// Staging writes ONLY s^1, reads ONLY s -> no intra-tile hazards.
// AM: 0 plain(lda)  1 y(64)|h_bt reversed, K=576  2 zk(128)|h_bt, K=640
// OM: 0 QRNN gates->f16 (tanh n<512, sigm else)  1 relu->f16  2 pair->f32
// ---------------------------------------------------------------------------
template <int AM, int OM>
__global__ __launch_bounds__(512, 2)
void gemm16_k(const f16* __restrict__ A0, const f16* __restrict__ A1,
              const f16* __restrict__ W0, const f16* __restrict__ W1,
              const float* __restrict__ bias, const float* __restrict__ bias2,
              float* __restrict__ C, float* __restrict__ C2,
              f16* __restrict__ Ch, int N, int K, int lda, int ntx) {
  __shared__ __align__(16) char lds[131072];
  const int tid = threadIdx.x;
  const int l = tid & 63, w = tid >> 6;
  const int nwg = gridDim.x;
  int bid = blockIdx.x;
  bid = (bid & 7) * (nwg >> 3) + (bid >> 3);     // XCD-contiguous logical ids
  const int m0 = (bid / ntx) * 256;
  const int n0 = (bid % ntx) * 256;
  const int Nh = N >> 1;

  // staging pointers: operand tile = 2048 slots of 16B (256 rows x 8 chunks);
  // thread covers slots r*512+tid, r=0..3, for A and for B (8 GLL / tile).
  const f16 *pa[4], *pa2[4], *pb[4];
#pragma unroll
  for (int r = 0; r < 4; ++r) {
    const int s = r * 512 + tid;
    const int row = s >> 3, c = s & 7;
    const int kc8 = (c ^ (row & 7)) * 8;         // inverse-swizzled k offset
    const int m = m0 + row;
    if constexpr (AM == 0) {
      pa[r] = A0 + (size_t)m * lda + kc8;
      pa2[r] = nullptr;
    } else if constexpr (AM == 1) {
      const int t = m >> 8, b = m & 255;
      pa[r]  = A0 + (size_t)((127 - t) * 256 + b) * 64 + kc8;    // y (flip t)
      pa2[r] = A1 + (size_t)((b << 7) | (127 - t)) * 512 + kc8;  // h_bt (flip t)
    } else {
      pa[r]  = A0 + (size_t)m * 128 + kc8;                        // zk_h
      pa2[r] = A1 + (size_t)m * 512 + kc8;                        // h_bt
    }
    int n = n0 + row;
    if constexpr (OM == 2) n = n < N ? n : N - 1;                 // small-N clamp
    if constexpr (OM == 2) {
      pb[r] = (n < Nh ? W0 + (size_t)n * K : W1 + (size_t)(n - Nh) * K) + kc8;
    } else {
      pb[r] = W0 + (size_t)n * K + kc8;
    }
  }

  // fragment LDS byte offsets (within a slot). 16x16x32 frag: lane l covers
  // row (l&15), k = ks*32 + (l>>4)*8 -> chunk = ks*4 + (l>>4), XOR row&7.
  const int wr = w >> 2, wc = w & 3;
  int offA[8][2], offB[4][2];
#pragma unroll
  for (int mf = 0; mf < 8; ++mf) {
    const int row = wr * 128 + mf * 16 + (l & 15);
#pragma unroll
    for (int ks = 0; ks < 2; ++ks) {
      const int c = (ks * 4 + (l >> 4)) ^ (row & 7);
      offA[mf][ks] = row * 128 + c * 16;
    }
  }
#pragma unroll
  for (int nf = 0; nf < 4; ++nf) {
    const int row = wc * 64 + nf * 16 + (l & 15);
#pragma unroll
    for (int ks = 0; ks < 2; ++ks) {
      const int c = (ks * 4 + (l >> 4)) ^ (row & 7);
      offB[nf][ks] = row * 128 + c * 16;
    }
  }

  // bias per nf (drain-style vmcnt below makes exact ledger unnecessary)
  float bv[4];
#pragma unroll
  for (int nf = 0; nf < 4; ++nf) {
    int gcol = n0 + wc * 64 + nf * 16 + (l & 15);
    if constexpr (OM == 2) {
      const int gi = gcol < N ? gcol : N - 1;
      bv[nf] = (gi >= Nh) ? bias2[gi - Nh] : bias[gi];
    } else {
      bv[nf] = bias[gcol];
    }
  }

  // stage chunk-pair p of K-tile st into slot buf. p:0-1 A rows, 2-3 B rows.
  auto stage_chunk = [&](int st, int buf, int p) {
    char* dA = lds + buf * 65536;
    char* dB = dA + 32768;
#pragma unroll
    for (int q = 0; q < 2; ++q) {
      const int r = (p & 1) * 2 + q;
      if (p < 2) {
        const f16* ga;
        if constexpr (AM == 0)      ga = pa[r] + st * 64;
        else if constexpr (AM == 1) ga = (st == 0) ? pa[r] : (pa2[r] + (st - 1) * 64);
        else                        ga = (st < 2) ? (pa[r] + st * 64) : (pa2[r] + (st - 2) * 64);
        GLL(ga, dA + (r * 512 + w * 64) * 16);
      } else {
        GLL(pb[r] + st * 64, dB + (r * 512 + w * 64) * 16);
      }
    }
  };

  floatx4 acc[8][4] = {};
  const int nsteps = K >> 6;
  // prologue: fully stage tile 0 into slot 0
#pragma unroll
  for (int p = 0; p < 4; ++p) stage_chunk(0, 0, p);
  asm volatile("s_waitcnt vmcnt(0)" ::: "memory");
  __builtin_amdgcn_s_barrier();

  for (int t = 0; t < nsteps; ++t) {
    const int s = t & 1;
    const char* cA = lds + s * 65536;
    const char* cB = cA + 32768;
    const bool more = (t + 1 < nsteps);
    half8 bfr[4];
#pragma unroll
    for (int p = 0; p < 4; ++p) {
      if (more) stage_chunk(t + 1, s ^ 1, p);
      constexpr int dummy = 0; (void)dummy;
      const int ks = p >> 1;
      // frag reads (compiler inserts lgkmcnt before MFMA use)
      if ((p & 1) == 0) {
        bfr[0] = *(const half8*)(cB + offB[0][ks]);
        bfr[1] = *(const half8*)(cB + offB[1][ks]);
        bfr[2] = *(const half8*)(cB + offB[2][ks]);
        bfr[3] = *(const half8*)(cB + offB[3][ks]);
      }
      half8 afr[4];
#pragma unroll
      for (int mi = 0; mi < 4; ++mi)
        afr[mi] = *(const half8*)(cA + offA[(p & 1) * 4 + mi][ks]);
      __builtin_amdgcn_s_barrier();
      __builtin_amdgcn_s_setprio(1);
#pragma unroll
      for (int mi = 0; mi < 4; ++mi) {
#pragma unroll
        for (int nf = 0; nf < 4; ++nf) {
          acc[(p & 1) * 4 + mi][nf] = __builtin_amdgcn_mfma_f32_16x16x32_f16(
              afr[mi], bfr[nf], acc[(p & 1) * 4 + mi][nf], 0, 0, 0);
        }
      }
      __builtin_amdgcn_s_setprio(0);
      __builtin_amdgcn_s_barrier();
    }
    // tile boundary: own ds_reads done + next tile staged, then release slot s
    asm volatile("s_waitcnt lgkmcnt(0) vmcnt(0)" ::: "memory");
    __builtin_amdgcn_s_barrier();
  }

  // epilogue: 16x16 C/D layout col = lane&15, row = (lane>>4)*4 + reg  [m89]
  const int r0 = (l >> 4) * 4;
#pragma unroll
  for (int nf = 0; nf < 4; ++nf) {
    const int gcol = n0 + wc * 64 + nf * 16 + (l & 15);
    if constexpr (OM == 2) {
      if (gcol < N) {
        const bool second = gcol >= Nh;
        float* cp = second ? C2 : C;
        const int cl = second ? gcol - Nh : gcol;
#pragma unroll
        for (int mf = 0; mf < 8; ++mf) {
#pragma unroll
          for (int reg = 0; reg < 4; ++reg) {
            const int grow = m0 + wr * 128 + mf * 16 + r0 + reg;
            const float v = acc[mf][nf][reg] + bv[nf];
            cp[(size_t)grow * Nh + cl] = second ? fsoftplus_(v) : fsig_(v);
          }
        }
      }
    } else {
#pragma unroll
      for (int mf = 0; mf < 8; ++mf) {
#pragma unroll
        for (int reg = 0; reg < 4; ++reg) {
          const int grow = m0 + wr * 128 + mf * 16 + r0 + reg;
          const float v = acc[mf][nf][reg] + bv[nf];
          float rr;
          if constexpr (OM == 0) rr = (gcol < 512) ? ftanh_(v) : fsig_(v);
          else                   rr = fmaxf(v, 0.f);
          Ch[(size_t)grow * N + gcol] = (f16)rr;
        }
      }
    }
  }
}

// ---------------------------------------------------------------------------
// Forget-mult scan, software-pipelined (prefetch t+1 while computing t).
// Y: (t,b,1536) f16, gates pre-activated.
// MODE 0: write h_bt[(b<<7)|t].  MODE 1: write arev[(b<<7)|(127-t)].
// ---------------------------------------------------------------------------
template <int MODE>
__global__ __launch_bounds__(256)
void scan_k(const f16* __restrict__ Y, f16* __restrict__ H1) {
  const int idx = blockIdx.x * 256 + threadIdx.x;   // 65536
  const int b = idx >> 8;
  const int h0 = (idx & 255) * 2;
  float c0 = 0.f, c1 = 0.f;
  const f16* pt = Y + (size_t)b * 1536 + h0;
  f16x2 zv = *(const f16x2*)(pt);
  f16x2 fv = *(const f16x2*)(pt + 512);
  f16x2 ov = *(const f16x2*)(pt + 1024);
  for (int t = 0; t < 128; ++t) {
    const f16* nx = pt + 256 * 1536;
    f16x2 zn, fn, on;
    if (t < 127) {                    // prefetch next step (hides HBM latency)
      zn = *(const f16x2*)(nx);
      fn = *(const f16x2*)(nx + 512);
      on = *(const f16x2*)(nx + 1024);
    }
    const float f0 = (float)fv[0], f1 = (float)fv[1];
    c0 = f0 * (float)zv[0] + (1.f - f0) * c0;
    c1 = f1 * (float)zv[1] + (1.f - f1) * c1;
    f16x2 hv = {(f16)((float)ov[0] * c0), (f16)((float)ov[1] * c1)};
    const int tt = (MODE == 0) ? t : (127 - t);
    *(f16x2*)(H1 + (size_t)((b << 7) | tt) * 512 + h0) = hv;
    zv = zn; fv = fn; ov = on;
    pt = nx;
  }
}

// ---------------------------------------------------------------------------
__global__ __launch_bounds__(256)
void z0_k(const float* __restrict__ mean, const float* __restrict__ sd,
          const float* __restrict__ eps, float* __restrict__ z) {
  const int i = blockIdx.x * 256 + threadIdx.x;
  const float4 m = ((const float4*)mean)[i];
  const float4 s = ((const float4*)sd)[i];
  const float4 e = ((const float4*)eps)[i];
  ((float4*)z)[i] = make_float4(m.x + s.x * e.x, m.y + s.y * e.y,
                                m.z + s.z * e.z, m.w + s.w * e.w);
}

__global__ __launch_bounds__(64)
void flow_pre_k(const float* __restrict__ u, const float* __restrict__ w,
                float* __restrict__ uhat, float* __restrict__ wu) {
  const int k = blockIdx.x, l = threadIdx.x;
  const float w0 = w[k * 128 + l], w1 = w[k * 128 + 64 + l];
  const float u0 = u[k * 128 + l], u1 = u[k * 128 + 64 + l];
  float nrm = w0 * w0 + w1 * w1;
  float udw = u0 * w0 + u1 * w1;
#pragma unroll
  for (int o = 32; o; o >>= 1) { nrm += __shfl_xor(nrm, o); udw += __shfl_xor(udw, o); }
  const float inv = 1.f / sqrtf(nrm);
  const float coef = (fsoftplus_(udw) - 1.f) - udw;
  const float uh0 = coef * (w0 * inv) + u0;
  const float uh1 = coef * (w1 * inv) + u1;
  uhat[k * 128 + l] = uh0;
  uhat[k * 128 + 64 + l] = uh1;
  float dwu = w0 * uh0 + w1 * uh1;
#pragma unroll
  for (int o = 32; o; o >>= 1) dwu += __shfl_xor(dwu, o);
  if (l == 0) wu[k] = dwu;
}

__global__ __launch_bounds__(256)
void flow_k(float* __restrict__ z, const float* __restrict__ w,
            const float* __restrict__ b, const float* __restrict__ uhat,
            const float* __restrict__ wu, float* __restrict__ sldj,
            f16* __restrict__ zh) {
  const int row = blockIdx.x * 4 + (threadIdx.x >> 6);
  const int l = threadIdx.x & 63;
  float* zp = z + (size_t)row * 128;
  float z0 = zp[l], z1 = zp[64 + l];
  float sl = 0.f;
#pragma unroll
  for (int k = 0; k < 16; ++k) {
    const float w0 = w[k * 128 + l], w1 = w[k * 128 + 64 + l];
    float s = z0 * w0 + z1 * w1;
#pragma unroll
    for (int o = 32; o; o >>= 1) s += __shfl_xor(s, o);
    const float t = ftanh_(s + b[k]);
    z0 += uhat[k * 128 + l] * t;
    z1 += uhat[k * 128 + 64 + l] * t;
    const float psi = (1.f - t * t) * wu[k];
    sl -= kLn2 * flog2_(fabsf(psi + 1.f) + 1e-8f);
  }
  zp[l] = z0;
  zp[64 + l] = z1;
  zh[(size_t)row * 128 + l] = (f16)z0;
  zh[(size_t)row * 128 + 64 + l] = (f16)z1;
  if (l == 0) sldj[row] = sl;
}

}  // namespace

extern "C" void kernel_launch(void* const* d_in, const int* in_sizes, int n_in,
                              void* d_out, int out_size, void* d_ws, size_t ws_size,
                              hipStream_t stream) {
  const float* x           = (const float*)d_in[0];
  const float* y           = (const float*)d_in[1];
  const float* eps         = (const float*)d_in[2];
  const float* hs_b        = (const float*)d_in[4];
  const float* q_b         = (const float*)d_in[6];
  const float* enc_phi_b   = (const float*)d_in[8];
  const float* enc_mean_b  = (const float*)d_in[10];
  const float* enc_std_b   = (const float*)d_in[12];
  const float* prior_phi_b = (const float*)d_in[14];
  const float* prior_mean_b= (const float*)d_in[16];
  const float* prior_std_b = (const float*)d_in[18];
  const float* dec_b1      = (const float*)d_in[20];
  const float* dec_b2      = (const float*)d_in[22];
  const float* dec_mean_b  = (const float*)d_in[24];
  const float* dec_std_b   = (const float*)d_in[26];
  const float* pnf_u       = (const float*)d_in[27];
  const float* pnf_w       = (const float*)d_in[28];
  const float* pnf_b       = (const float*)d_in[29];

  float* out = (float*)d_out;
  float* dec_mean  = out;
  float* dec_std   = out + 2097152;
  float* enc_mean  = out + 4194304;
  float* enc_std   = out + 8388608;
  float* prior_mean= out + 12582912;
  float* prior_std = out + 16777216;
  float* zk        = out + 20971520;
  float* sldj      = out + 25165824;

  // ---- workspace layout (bytes) ----
  char* ws = (char*)d_ws;
  f16* Ybuf  = (f16*)(ws + 0);             // (128,256,1536) f16 = 100.7 MB
  f16* e1    = (f16*)(ws + 0);             // alias (Y dead after scans)
  f16* e2    = (f16*)(ws + 33554432);      // alias
  f16* arev  = (f16*)(ws + 100663296);
  f16* h_bt  = (f16*)(ws + 134217728);
  f16* zk_h  = (f16*)(ws + 167772160);
  f16* xh    = (f16*)(ws + 176160768);
  f16* yh    = (f16*)(ws + 180355072);
  f16* wbuf  = (f16*)(ws + 184549376);
  float* uhat= (float*)(ws + 190447616);
  float* wu  = (float*)(ws + 190455808);

  f16* w_hs   = wbuf + 0;
  f16* w_q    = wbuf + 98304;
  f16* w_ephi = wbuf + 983040;
  f16* w_emean= wbuf + 1507328;
  f16* w_estd = wbuf + 1572864;
  f16* w_pphi = wbuf + 1638400;
  f16* w_pmean= wbuf + 2162688;
  f16* w_pstd = wbuf + 2228224;
  f16* w_d1   = wbuf + 2293760;
  f16* w_d2   = wbuf + 2621440;
  f16* w_dmean= wbuf + 2883584;
  f16* w_dstd = wbuf + 2916352;

  CvtTab tab;
  const float* srcs[14] = {x, y, (const float*)d_in[3], (const float*)d_in[5],
                           (const float*)d_in[7], (const float*)d_in[9],
                           (const float*)d_in[11], (const float*)d_in[13],
                           (const float*)d_in[15], (const float*)d_in[17],
                           (const float*)d_in[19], (const float*)d_in[21],
                           (const float*)d_in[23], (const float*)d_in[25]};
  f16* dsts[14] = {xh, yh, w_hs, w_q, w_ephi, w_emean, w_estd, w_pphi,
                   w_pmean, w_pstd, w_d1, w_d2, w_dmean, w_dstd};
  const int ns[14] = {2097152, 2097152, 98304, 884736, 524288, 65536, 65536,
                      524288, 65536, 65536, 327680, 262144, 32768, 32768};
  for (int i = 0; i < 14; ++i) { tab.s[i] = srcs[i]; tab.d[i] = dsts[i]; tab.n4[i] = ns[i] >> 2; }
  cvt_k<<<dim3(128, 14), 256, 0, stream>>>(tab);

  const dim3 blk(512);

  // ---- QRNN 1 (hidden-state): N=1536, K=64, ntx=6 -> 768 blocks ----
  gemm16_k<0, 0><<<768, blk, 0, stream>>>(xh, nullptr, w_hs, nullptr,
      hs_b, nullptr, nullptr, nullptr, Ybuf, 1536, 64, 64, 6);
  scan_k<0><<<256, 256, 0, stream>>>(Ybuf, h_bt);

  // ---- QRNN 2 (inference, reversed [y,h]): K=576 ----
  gemm16_k<1, 0><<<768, blk, 0, stream>>>(yh, h_bt, w_q, nullptr,
      q_b, nullptr, nullptr, nullptr, Ybuf, 1536, 576, 0, 6);
  scan_k<1><<<256, 256, 0, stream>>>(Ybuf, arev);

  // ---- encoder ----
  gemm16_k<0, 1><<<256, blk, 0, stream>>>(arev, nullptr, w_ephi, nullptr,
      enc_phi_b, nullptr, nullptr, nullptr, e1, 512, 512, 512, 2);
  gemm16_k<0, 1><<<256, blk, 0, stream>>>(e1, nullptr, w_ephi + 262144, nullptr,
      enc_phi_b + 512, nullptr, nullptr, nullptr, e2, 512, 512, 512, 2);
  gemm16_k<0, 2><<<128, blk, 0, stream>>>(e2, nullptr, w_emean, w_estd,
      enc_mean_b, enc_std_b, enc_mean, enc_std, nullptr, 256, 512, 512, 1);
  z0_k<<<4096, 256, 0, stream>>>(enc_mean, enc_std, eps, zk);
  flow_pre_k<<<16, 64, 0, stream>>>(pnf_u, pnf_w, uhat, wu);
  flow_k<<<8192, 256, 0, stream>>>(zk, pnf_w, pnf_b, uhat, wu, sldj, zk_h);

  // ---- prior ----
  gemm16_k<0, 1><<<256, blk, 0, stream>>>(h_bt, nullptr, w_pphi, nullptr,
      prior_phi_b, nullptr, nullptr, nullptr, e1, 512, 512, 512, 2);
  gemm16_k<0, 1><<<256, blk, 0, stream>>>(e1, nullptr, w_pphi + 262144, nullptr,
      prior_phi_b + 512, nullptr, nullptr, nullptr, e2, 512, 512, 512, 2);
  gemm16_k<0, 2><<<128, blk, 0, stream>>>(e2, nullptr, w_pmean, w_pstd,
      prior_mean_b, prior_std_b, prior_mean, prior_std, nullptr, 256, 512, 512, 1);

  // ---- decoder ----
  gemm16_k<2, 1><<<256, blk, 0, stream>>>(zk_h, h_bt, w_d1, nullptr,
      dec_b1, nullptr, nullptr, nullptr, e1, 512, 640, 0, 2);
  gemm16_k<0, 1><<<256, blk, 0, stream>>>(e1, nullptr, w_d2, nullptr,
      dec_b2, nullptr, nullptr, nullptr, e2, 512, 512, 512, 2);
  gemm16_k<0, 2><<<128, blk, 0, stream>>>(e2, nullptr, w_dmean, w_dstd,
      dec_mean_b, dec_std_b, dec_mean, dec_std, nullptr, 128, 512, 512, 1);
}